// Round 2
// baseline (1074.850 us; speedup 1.0000x reference)
//
#include <hip/hip_runtime.h>

typedef __attribute__((ext_vector_type(8))) short short8;
typedef __attribute__((ext_vector_type(4))) float f32x4;

#define SCALE_Q 0.17677669529663687f  // 32^-0.5

__device__ __forceinline__ unsigned short f2bf(float f){
  unsigned u = __builtin_bit_cast(unsigned, f);
  u = (u + 0x7FFFu + ((u >> 16) & 1u)) >> 16;
  return (unsigned short)u;
}
__device__ __forceinline__ float bf2f(unsigned short h){
  unsigned u = ((unsigned)h) << 16;
  return __builtin_bit_cast(float, u);
}

// ---------------- weight prep: fold LN affine + q-scale, convert to bf16 ----------------
__global__ void prep_w(const float* __restrict__ w_qkv, const float* __restrict__ g,
                       const float* __restrict__ bvec, const float* __restrict__ w_out,
                       unsigned short* __restrict__ wq_b, unsigned short* __restrict__ wo_b,
                       float* __restrict__ qkvb){
  const int row  = blockIdx.x * 4 + (threadIdx.x >> 6);  // 0..1023
  const int lane = threadIdx.x & 63;
  if (row < 768){
    const float sc = (row < 256) ? SCALE_Q : 1.0f;
    float4 w  = ((const float4*)(w_qkv + (size_t)row * 256))[lane];
    float4 gv = ((const float4*)g)[lane];
    float4 bv = ((const float4*)bvec)[lane];
    unsigned long long pk =
        (unsigned long long)f2bf(w.x * gv.x * sc)
      | ((unsigned long long)f2bf(w.y * gv.y * sc) << 16)
      | ((unsigned long long)f2bf(w.z * gv.z * sc) << 32)
      | ((unsigned long long)f2bf(w.w * gv.w * sc) << 48);
    *(unsigned long long*)(wq_b + (size_t)row * 256 + lane * 4) = pk;
    float acc = w.x * bv.x + w.y * bv.y + w.z * bv.z + w.w * bv.w;
    #pragma unroll
    for (int off = 32; off; off >>= 1) acc += __shfl_xor(acc, off);
    if (lane == 0) qkvb[row] = acc * sc;
  } else {
    const int o = row - 768;
    float4 w = ((const float4*)(w_out + (size_t)o * 256))[lane];
    unsigned long long pk =
        (unsigned long long)f2bf(w.x)
      | ((unsigned long long)f2bf(w.y) << 16)
      | ((unsigned long long)f2bf(w.z) << 32)
      | ((unsigned long long)f2bf(w.w) << 48);
    *(unsigned long long*)(wo_b + (size_t)o * 256 + lane * 4) = pk;
  }
}

// ---------------- dynamic position bias MLP: 289 coords -> table ----------------
__device__ __forceinline__ float wsum(float v){
  #pragma unroll
  for (int off = 32; off; off >>= 1) v += __shfl_xor(v, off);
  return v;
}
__device__ __forceinline__ float lnrelu(float h, float gamma, float beta){
  float m = wsum(h) * (1.0f / 64.0f);
  float d = h - m;
  float v = wsum(d * d) * (1.0f / 64.0f);
  float r = d * rsqrtf(v + 1e-5f) * gamma + beta;
  return fmaxf(r, 0.0f);
}
__device__ __forceinline__ float matmul64(float h, const float* __restrict__ w, int f){
  float acc = 0.0f;
  for (int k = 0; k < 64; ++k) acc += __shfl(h, k) * w[k * 64 + f];
  return acc;
}

__global__ void dpb_kernel(const float* __restrict__ w1, const float* __restrict__ b1,
                           const float* __restrict__ g1, const float* __restrict__ e1,
                           const float* __restrict__ w2, const float* __restrict__ b2,
                           const float* __restrict__ g2, const float* __restrict__ e2,
                           const float* __restrict__ w3, const float* __restrict__ b3,
                           const float* __restrict__ g3, const float* __restrict__ e3,
                           const float* __restrict__ w4, const float* __restrict__ b4,
                           float* __restrict__ table){
  const int r = blockIdx.x, f = threadIdx.x;
  const float cy = (float)(r / 17 - 8), cx = (float)(r % 17 - 8);
  float h = cy * w1[f] + cx * w1[64 + f] + b1[f];
  h = lnrelu(h, g1[f], e1[f]);
  float h2 = matmul64(h, w2, f) + b2[f];
  h2 = lnrelu(h2, g2[f], e2[f]);
  float h3 = matmul64(h2, w3, f) + b3[f];
  h3 = lnrelu(h3, g3[f], e3[f]);
  float o = wsum(h3 * w4[f]);
  if (f == 0) table[r] = o + b4[0];
}

__global__ void bias_expand(const float* __restrict__ table, float* __restrict__ bias64){
  const int id = blockIdx.x * 256 + threadIdx.x;  // 0..4095
  const int i = id >> 6, j = id & 63;
  const int r0 = (i >> 3) - (j >> 3) + 7;
  const int r1 = (i & 7) - (j & 7) + 7;
  bias64[id] = table[r0 * 15 + r1];
}

// ---------------- fused main kernel: 1 block = 1 window ----------------
// LDS layout (bytes):
//   0      : xn  [64][264] bf16 (33792) ; later P per-wave @ wv*9216 [64][72]; later ao [64][264]
//   36864  : Qs  [64][264] bf16
//   70656  : Ks  [64][264] bf16
//   104448 : Vt  [256][72] bf16 (V transposed: [dim][token])
//   141312 : red: 640 floats (LN partials + mean/rstd)
//   143872 : scr: 4 waves * 288 floats ([16][17] transpose scratch)
// total 148480
#define LDS_TOTAL 148480

__global__ __launch_bounds__(256, 1) void attn_main(
    const float* __restrict__ x,
    const unsigned short* __restrict__ wq_b,
    const unsigned short* __restrict__ wo_b,
    const float* __restrict__ qkvb,
    const float* __restrict__ b_out,
    const float* __restrict__ bias64,
    float* __restrict__ out)
{
  extern __shared__ char smem[];
  unsigned short* xn = (unsigned short*)smem;             // [64][264]
  unsigned short* Qs = (unsigned short*)(smem + 36864);   // [64][264]
  unsigned short* Ks = (unsigned short*)(smem + 70656);   // [64][264]
  unsigned short* Vt = (unsigned short*)(smem + 104448);  // [256][72]

  const int tid = threadIdx.x, lane = tid & 63, wv = tid >> 6;
  // XCD-locality swizzle: contiguous 512-window chunks per XCD (4096 % 8 == 0)
  const int blk = ((blockIdx.x & 7) << 9) | (blockIdx.x >> 3);
  const int b = blk >> 10, hb = (blk >> 5) & 31, wb = blk & 31;

  // ---- Phase 1: load window + channel LayerNorm -> xn (bf16) ----
  {
    const int p = lane, prow = p >> 3, pcol = p & 7;
    const float* xp = x + ((size_t)b << 24) + (size_t)(hb * 8 + prow) * 256 + (size_t)(wb * 8 + pcol);
    float sum = 0.0f, ss = 0.0f;
    unsigned short* xrow = xn + p * 264;
    #pragma unroll 8
    for (int dk = 0; dk < 64; ++dk){
      const int d = (wv << 6) + dk;
      float v = xp[(size_t)d << 16];
      sum += v; ss += v * v;
      xrow[d] = f2bf(v);
    }
    float* red = (float*)(smem + 141312);
    red[wv * 64 + p] = sum;
    red[256 + wv * 64 + p] = ss;
    __syncthreads();
    float s0 = red[p] + red[64 + p] + red[128 + p] + red[192 + p];
    float s1 = red[256 + p] + red[320 + p] + red[384 + p] + red[448 + p];
    float mean = s0 * (1.0f / 256.0f);
    float var  = s1 * (1.0f / 256.0f) - mean * mean;
    float rstd = rsqrtf(var + 1e-5f);
    if (wv == 0){ red[512 + p] = mean; red[576 + p] = rstd; }
    __syncthreads();
    const int pp = tid >> 2, qq = tid & 3;
    const float mn = red[512 + pp], rs = red[576 + pp];
    unsigned short* rowp = xn + pp * 264 + qq * 64;
    #pragma unroll
    for (int i = 0; i < 8; ++i){
      short8 v8 = *(short8*)(rowp + i * 8);
      #pragma unroll
      for (int e = 0; e < 8; ++e){
        float f = bf2f((unsigned short)v8[e]);
        v8[e] = (short)f2bf((f - mn) * rs);
      }
      *(short8*)(rowp + i * 8) = v8;
    }
  }
  __syncthreads();

  // ---- Phase 2: QKV projection (M=64, N=768, K=256), wave nt-partition ----
  {
    const int l15 = lane & 15, l4 = lane >> 4;
    for (int c = 0; c < 3; ++c){
      const int n0 = wv * 192 + c * 64;
      f32x4 acc[4][4];
      #pragma unroll
      for (int mt = 0; mt < 4; ++mt)
        #pragma unroll
        for (int nt = 0; nt < 4; ++nt)
          acc[mt][nt] = (f32x4){0.f, 0.f, 0.f, 0.f};
      const unsigned short* bp = wq_b + (size_t)(n0 + l15) * 256 + 8 * l4;
      short8 bcur[4], bnxt[4];
      #pragma unroll
      for (int nt = 0; nt < 4; ++nt) bcur[nt] = *(const short8*)(bp + nt * 4096);
      #pragma unroll
      for (int kt = 0; kt < 8; ++kt){
        if (kt < 7){
          #pragma unroll
          for (int nt = 0; nt < 4; ++nt) bnxt[nt] = *(const short8*)(bp + nt * 4096 + (kt + 1) * 32);
        }
        short8 a[4];
        #pragma unroll
        for (int mt = 0; mt < 4; ++mt)
          a[mt] = *(const short8*)(xn + (mt * 16 + l15) * 264 + kt * 32 + 8 * l4);
        #pragma unroll
        for (int mt = 0; mt < 4; ++mt)
          #pragma unroll
          for (int nt = 0; nt < 4; ++nt)
            acc[mt][nt] = __builtin_amdgcn_mfma_f32_16x16x32_bf16(a[mt], bcur[nt], acc[mt][nt], 0, 0, 0);
        if (kt < 7){
          #pragma unroll
          for (int nt = 0; nt < 4; ++nt) bcur[nt] = bnxt[nt];
        }
      }
      const bool isV = (n0 >= 512);
      const bool isQ = (n0 < 256);
      #pragma unroll
      for (int nt = 0; nt < 4; ++nt){
        const int e = n0 + nt * 16 + l15;
        const float bv = qkvb[e];
        #pragma unroll
        for (int mt = 0; mt < 4; ++mt){
          if (!isV){
            unsigned short* dst = isQ ? Qs : Ks;
            const int col = e & 255;
            #pragma unroll
            for (int j = 0; j < 4; ++j){
              const int row = mt * 16 + (l4 << 2) + j;
              dst[row * 264 + col] = f2bf(acc[mt][nt][j] + bv);
            }
          } else {
            const int vd = e - 512;
            const int r0 = mt * 16 + (l4 << 2);
            unsigned long long pk =
                (unsigned long long)f2bf(acc[mt][nt][0] + bv)
              | ((unsigned long long)f2bf(acc[mt][nt][1] + bv) << 16)
              | ((unsigned long long)f2bf(acc[mt][nt][2] + bv) << 32)
              | ((unsigned long long)f2bf(acc[mt][nt][3] + bv) << 48);
            *(unsigned long long*)(Vt + vd * 72 + r0) = pk;
          }
        }
      }
    }
  }
  __syncthreads();

  // ---- Phase 3: per-wave attention over 2 heads ----
  {
    const int l15 = lane & 15, l4 = lane >> 4;
    unsigned short* Pw = ((unsigned short*)smem) + wv * 4608;  // [64][72] bf16, overlaps dead xn
    f32x4 oacc[2][4][2];
    #pragma unroll
    for (int hh = 0; hh < 2; ++hh){
      const int h = (wv << 1) + hh;
      short8 qa[4], kb[4];
      #pragma unroll
      for (int t = 0; t < 4; ++t){
        qa[t] = *(const short8*)(Qs + (t * 16 + l15) * 264 + h * 32 + 8 * l4);
        kb[t] = *(const short8*)(Ks + (t * 16 + l15) * 264 + h * 32 + 8 * l4);
      }
      #pragma unroll
      for (int mt = 0; mt < 4; ++mt){
        f32x4 srow[4];
        #pragma unroll
        for (int nt = 0; nt < 4; ++nt){
          f32x4 z = {0.f, 0.f, 0.f, 0.f};
          srow[nt] = __builtin_amdgcn_mfma_f32_16x16x32_bf16(qa[mt], kb[nt], z, 0, 0, 0);
        }
        #pragma unroll
        for (int j = 0; j < 4; ++j){
          const int row = mt * 16 + (l4 << 2) + j;
          float v0 = srow[0][j] + bias64[row * 64 +      l15];
          float v1 = srow[1][j] + bias64[row * 64 + 16 + l15];
          float v2 = srow[2][j] + bias64[row * 64 + 32 + l15];
          float v3 = srow[3][j] + bias64[row * 64 + 48 + l15];
          float m = fmaxf(fmaxf(v0, v1), fmaxf(v2, v3));
          m = fmaxf(m, __shfl_xor(m, 1)); m = fmaxf(m, __shfl_xor(m, 2));
          m = fmaxf(m, __shfl_xor(m, 4)); m = fmaxf(m, __shfl_xor(m, 8));
          v0 = __expf(v0 - m); v1 = __expf(v1 - m);
          v2 = __expf(v2 - m); v3 = __expf(v3 - m);
          float sm = v0 + v1 + v2 + v3;
          sm += __shfl_xor(sm, 1); sm += __shfl_xor(sm, 2);
          sm += __shfl_xor(sm, 4); sm += __shfl_xor(sm, 8);
          const float inv = 1.0f / sm;
          Pw[row * 72 +      l15] = f2bf(v0 * inv);
          Pw[row * 72 + 16 + l15] = f2bf(v1 * inv);
          Pw[row * 72 + 32 + l15] = f2bf(v2 * inv);
          Pw[row * 72 + 48 + l15] = f2bf(v3 * inv);
        }
      }
      #pragma unroll
      for (int mt = 0; mt < 4; ++mt)
        #pragma unroll
        for (int nt = 0; nt < 2; ++nt)
          oacc[hh][mt][nt] = (f32x4){0.f, 0.f, 0.f, 0.f};
      #pragma unroll
      for (int kt = 0; kt < 2; ++kt){
        short8 pa[4], vb[2];
        #pragma unroll
        for (int mt = 0; mt < 4; ++mt)
          pa[mt] = *(const short8*)(Pw + (mt * 16 + l15) * 72 + kt * 32 + 8 * l4);
        #pragma unroll
        for (int nt = 0; nt < 2; ++nt)
          vb[nt] = *(const short8*)(Vt + (h * 32 + nt * 16 + l15) * 72 + kt * 32 + 8 * l4);
        #pragma unroll
        for (int mt = 0; mt < 4; ++mt)
          #pragma unroll
          for (int nt = 0; nt < 2; ++nt)
            oacc[hh][mt][nt] = __builtin_amdgcn_mfma_f32_16x16x32_bf16(pa[mt], vb[nt], oacc[hh][mt][nt], 0, 0, 0);
      }
    }
    __syncthreads();   // all P consumed -> safe to overwrite region 0 with ao
    unsigned short* ao = (unsigned short*)smem;  // [64][264]
    #pragma unroll
    for (int hh = 0; hh < 2; ++hh){
      const int h = (wv << 1) + hh;
      #pragma unroll
      for (int mt = 0; mt < 4; ++mt)
        #pragma unroll
        for (int nt = 0; nt < 2; ++nt)
          #pragma unroll
          for (int j = 0; j < 4; ++j)
            ao[(mt * 16 + (l4 << 2) + j) * 264 + h * 32 + nt * 16 + l15] = f2bf(oacc[hh][mt][nt][j]);
    }
  }
  __syncthreads();

  // ---- Phase 4: out projection (M=64, N=256, K=256) + coalesced store ----
  {
    const int l15 = lane & 15, l4 = lane >> 4;
    const unsigned short* ao = (const unsigned short*)smem;
    float* sw = (float*)(smem + 143872) + wv * 288;  // [16][17] transpose scratch
    const int n0w = wv * 64;
    f32x4 acc[4][4];
    #pragma unroll
    for (int mt = 0; mt < 4; ++mt)
      #pragma unroll
      for (int nt = 0; nt < 4; ++nt)
        acc[mt][nt] = (f32x4){0.f, 0.f, 0.f, 0.f};
    const unsigned short* bp = wo_b + (size_t)(n0w + l15) * 256 + 8 * l4;
    short8 bcur[4], bnxt[4];
    #pragma unroll
    for (int nt = 0; nt < 4; ++nt) bcur[nt] = *(const short8*)(bp + nt * 4096);
    #pragma unroll
    for (int kt = 0; kt < 8; ++kt){
      if (kt < 7){
        #pragma unroll
        for (int nt = 0; nt < 4; ++nt) bnxt[nt] = *(const short8*)(bp + nt * 4096 + (kt + 1) * 32);
      }
      short8 a[4];
      #pragma unroll
      for (int mt = 0; mt < 4; ++mt)
        a[mt] = *(const short8*)(ao + (mt * 16 + l15) * 264 + kt * 32 + 8 * l4);
      #pragma unroll
      for (int mt = 0; mt < 4; ++mt)
        #pragma unroll
        for (int nt = 0; nt < 4; ++nt)
          acc[mt][nt] = __builtin_amdgcn_mfma_f32_16x16x32_bf16(a[mt], bcur[nt], acc[mt][nt], 0, 0, 0);
      if (kt < 7){
        #pragma unroll
        for (int nt = 0; nt < 4; ++nt) bcur[nt] = bnxt[nt];
      }
    }
    float* op = out + ((size_t)b << 24) + (size_t)(hb * 8) * 256 + (size_t)(wb * 8);
    #pragma unroll
    for (int nt = 0; nt < 4; ++nt){
      const int ebase = n0w + nt * 16;
      const float bo = b_out[ebase + l15];
      #pragma unroll
      for (int mt = 0; mt < 4; ++mt){
        #pragma unroll
        for (int j = 0; j < 4; ++j)
          sw[((l4 << 2) + j) * 17 + l15] = acc[mt][nt][j] + bo;
        asm volatile("s_waitcnt lgkmcnt(0)" ::: "memory");
        #pragma unroll
        for (int q = 0; q < 4; ++q){
          const int el = q * 4 + l4;
          float v = sw[l15 * 17 + el];
          const int p = mt * 16 + l15;
          op[(size_t)(ebase + el) * 65536 + (size_t)(p >> 3) * 256 + (p & 7)] = v;
        }
        asm volatile("s_waitcnt lgkmcnt(0)" ::: "memory");
      }
    }
  }
}

extern "C" void kernel_launch(void* const* d_in, const int* in_sizes, int n_in,
                              void* d_out, int out_size, void* d_ws, size_t ws_size,
                              hipStream_t stream){
  const float* x     = (const float*)d_in[0];
  const float* g     = (const float*)d_in[1];
  const float* bvec  = (const float*)d_in[2];
  const float* w_qkv = (const float*)d_in[3];
  const float* w_out = (const float*)d_in[4];
  const float* b_out = (const float*)d_in[5];
  float* out = (float*)d_out;

  char* ws = (char*)d_ws;
  unsigned short* wq_b  = (unsigned short*)(ws);            // 768*256 bf16
  unsigned short* wo_b  = (unsigned short*)(ws + 393216);   // 256*256 bf16
  float* qkvb   = (float*)(ws + 524288);                    // 768 f32
  float* table  = (float*)(ws + 527360);                    // 289 f32
  float* bias64 = (float*)(ws + 528640);                    // 4096 f32

  prep_w<<<dim3(256), dim3(256), 0, stream>>>(w_qkv, g, bvec, w_out, wq_b, wo_b, qkvb);
  dpb_kernel<<<dim3(289), dim3(64), 0, stream>>>(
      (const float*)d_in[6],  (const float*)d_in[7],  (const float*)d_in[8],  (const float*)d_in[9],
      (const float*)d_in[10], (const float*)d_in[11], (const float*)d_in[12], (const float*)d_in[13],
      (const float*)d_in[14], (const float*)d_in[15], (const float*)d_in[16], (const float*)d_in[17],
      (const float*)d_in[18], (const float*)d_in[19], table);
  bias_expand<<<dim3(16), dim3(256), 0, stream>>>(table, bias64);

  hipFuncSetAttribute((const void*)attn_main, hipFuncAttributeMaxDynamicSharedMemorySize, LDS_TOTAL);
  attn_main<<<dim3(4096), dim3(256), LDS_TOTAL, stream>>>(x, wq_b, wo_b, qkvb, b_out, bias64, out);
}

// Round 3
// 862.159 us; speedup vs baseline: 1.2467x; 1.2467x over previous
//
#include <hip/hip_runtime.h>

typedef __attribute__((ext_vector_type(8))) short short8;
typedef __attribute__((ext_vector_type(4))) float f32x4;

#define SCALE_Q 0.17677669529663687f  // 32^-0.5

__device__ __forceinline__ unsigned short f2bf(float f){
  unsigned u = __builtin_bit_cast(unsigned, f);
  u = (u + 0x7FFFu + ((u >> 16) & 1u)) >> 16;
  return (unsigned short)u;
}
__device__ __forceinline__ float bf2f(unsigned short h){
  unsigned u = ((unsigned)h) << 16;
  return __builtin_bit_cast(float, u);
}

// ---------------- weight prep: MFMA-tiled bf16 layout ----------------
// wq_t: 48 tiles(16 cols) x 8 kt x 64 lanes x 8 bf16   (tile stride 4096 elems)
// wo_t: 16 tiles x 8 kt x 64 lanes x 8 bf16
// element (e, k): tile=e>>4, l15=e&15, kt=k>>5, l4=(k>>3)&3, i=k&7, lane=l4*16+l15
__global__ void prep_tiled(const float* __restrict__ w_qkv, const float* __restrict__ g,
                           const float* __restrict__ w_out,
                           unsigned short* __restrict__ wq_t, unsigned short* __restrict__ wo_t){
  int id = blockIdx.x * 256 + threadIdx.x;     // 0..32767
  const bool isQKV = (id < 24576);
  int e, sub;
  const float* src;
  unsigned short* dst;
  float sc;
  if (isQKV){ e = id >> 5; sub = id & 31; src = w_qkv; dst = wq_t; sc = (e < 256) ? SCALE_Q : 1.0f; }
  else { int id2 = id - 24576; e = id2 >> 5; sub = id2 & 31; src = w_out; dst = wo_t; sc = 1.0f; }
  const int kt = sub >> 2, l4c = sub & 3;
  const int k0 = kt * 32 + l4c * 8;
  const int tile = e >> 4, l15c = e & 15;
  const float4 w0 = *(const float4*)(src + (size_t)e * 256 + k0);
  const float4 w1 = *(const float4*)(src + (size_t)e * 256 + k0 + 4);
  float4 g0 = make_float4(1.f,1.f,1.f,1.f), g1 = g0;
  if (isQKV){ g0 = *(const float4*)(g + k0); g1 = *(const float4*)(g + k0 + 4); }
  short8 o;
  o[0] = (short)f2bf(w0.x * g0.x * sc); o[1] = (short)f2bf(w0.y * g0.y * sc);
  o[2] = (short)f2bf(w0.z * g0.z * sc); o[3] = (short)f2bf(w0.w * g0.w * sc);
  o[4] = (short)f2bf(w1.x * g1.x * sc); o[5] = (short)f2bf(w1.y * g1.y * sc);
  o[6] = (short)f2bf(w1.z * g1.z * sc); o[7] = (short)f2bf(w1.w * g1.w * sc);
  *(short8*)(dst + ((size_t)(tile * 8 + kt) * 64 + (l4c * 16 + l15c)) * 8) = o;
}

__global__ void qkvb_kernel(const float* __restrict__ w_qkv, const float* __restrict__ bvec,
                            float* __restrict__ qkvb){
  const int row = blockIdx.x * 4 + (threadIdx.x >> 6);  // 0..767
  const int lane = threadIdx.x & 63;
  float4 w  = ((const float4*)(w_qkv + (size_t)row * 256))[lane];
  float4 bv = ((const float4*)bvec)[lane];
  float acc = w.x * bv.x + w.y * bv.y + w.z * bv.z + w.w * bv.w;
  #pragma unroll
  for (int off = 32; off; off >>= 1) acc += __shfl_xor(acc, off);
  if (lane == 0) qkvb[row] = acc * ((row < 256) ? SCALE_Q : 1.0f);
}

// ---------------- dynamic position bias MLP ----------------
__device__ __forceinline__ float wsum(float v){
  #pragma unroll
  for (int off = 32; off; off >>= 1) v += __shfl_xor(v, off);
  return v;
}
__device__ __forceinline__ float lnrelu(float h, float gamma, float beta){
  float m = wsum(h) * (1.0f / 64.0f);
  float d = h - m;
  float v = wsum(d * d) * (1.0f / 64.0f);
  float r = d * rsqrtf(v + 1e-5f) * gamma + beta;
  return fmaxf(r, 0.0f);
}
__device__ __forceinline__ float matmul64(float h, const float* __restrict__ w, int f){
  float acc = 0.0f;
  for (int k = 0; k < 64; ++k) acc += __shfl(h, k) * w[k * 64 + f];
  return acc;
}

__global__ void dpb_kernel(const float* __restrict__ w1, const float* __restrict__ b1,
                           const float* __restrict__ g1, const float* __restrict__ e1,
                           const float* __restrict__ w2, const float* __restrict__ b2,
                           const float* __restrict__ g2, const float* __restrict__ e2,
                           const float* __restrict__ w3, const float* __restrict__ b3,
                           const float* __restrict__ g3, const float* __restrict__ e3,
                           const float* __restrict__ w4, const float* __restrict__ b4,
                           float* __restrict__ table){
  const int r = blockIdx.x, f = threadIdx.x;
  const float cy = (float)(r / 17 - 8), cx = (float)(r % 17 - 8);
  float h = cy * w1[f] + cx * w1[64 + f] + b1[f];
  h = lnrelu(h, g1[f], e1[f]);
  float h2 = matmul64(h, w2, f) + b2[f];
  h2 = lnrelu(h2, g2[f], e2[f]);
  float h3 = matmul64(h2, w3, f) + b3[f];
  h3 = lnrelu(h3, g3[f], e3[f]);
  float o = wsum(h3 * w4[f]);
  if (f == 0) table[r] = o + b4[0];
}

__global__ void bias_expand(const float* __restrict__ table, float* __restrict__ bias64){
  const int id = blockIdx.x * 256 + threadIdx.x;  // 0..4095
  const int i = id >> 6, j = id & 63;
  const int r0 = (i >> 3) - (j >> 3) + 7;
  const int r1 = (i & 7) - (j & 7) + 7;
  bias64[id] = table[r0 * 15 + r1];
}

// ---------------- fused main kernel: 1 block = 1 window, 16 waves ----------------
// LDS layout (bytes):
//   0      : xn  [64][264] bf16 (33792);  P3: Pw 8 heads x [64][64] swz (65536); P3-end: ao [64][264]
//   33792  : Qs  [64][264] bf16           P4: sw 16 waves x 288 f32 (18432) @33792
//   67584  : Ks  [64][264] bf16
//   101376 : Vt  [256][72] bf16
//   138240 : red 2176 floats (8704 B): sum[1024], ss[1024], mean[64], rstd[64]
// total 146944
#define LDS_TOTAL 146944

// P-buffer XOR swizzle: [64 rows][64 cols] bf16, 16B-chunk XOR by row&7.
__device__ __forceinline__ int pswz(int row, int col){  // offset in shorts
  return row * 64 + (((col >> 3) ^ (row & 7)) << 3) + (col & 7);
}

__global__ __launch_bounds__(1024, 1) void attn_main(
    const float* __restrict__ x,
    const unsigned short* __restrict__ wq_t,
    const unsigned short* __restrict__ wo_t,
    const float* __restrict__ qkvb,
    const float* __restrict__ b_out,
    const float* __restrict__ bias64,
    float* __restrict__ out)
{
  extern __shared__ char smem[];
  unsigned short* xn = (unsigned short*)smem;             // [64][264]
  unsigned short* Qs = (unsigned short*)(smem + 33792);   // [64][264]
  unsigned short* Ks = (unsigned short*)(smem + 67584);   // [64][264]
  unsigned short* Vt = (unsigned short*)(smem + 101376);  // [256][72]
  float* red = (float*)(smem + 138240);

  const int tid = threadIdx.x, lane = tid & 63, wv = tid >> 6;  // wv 0..15
  const int l15 = lane & 15, l4 = lane >> 4;
  const int blk = ((blockIdx.x & 7) << 9) | (blockIdx.x >> 3);
  const int b = blk >> 10, hb = (blk >> 5) & 31, wb = blk & 31;

  // ---- Phase 1: load window + channel LayerNorm -> xn (bf16) ----
  {
    const int p = lane, prow = p >> 3, pcol = p & 7;
    const float* xp = x + ((size_t)b << 24) + (size_t)(hb * 8 + prow) * 256 + (size_t)(wb * 8 + pcol);
    float sum = 0.0f, ss = 0.0f;
    unsigned short* xrow = xn + p * 264;
    #pragma unroll
    for (int i = 0; i < 16; ++i){
      const int d = (wv << 4) + i;
      float v = xp[(size_t)d << 16];
      sum += v; ss += v * v;
      xrow[d] = f2bf(v);
    }
    red[wv * 64 + p] = sum;
    red[1024 + wv * 64 + p] = ss;
    __syncthreads();
    if (wv == 0){
      float s0 = 0.f, s1 = 0.f;
      #pragma unroll
      for (int w = 0; w < 16; ++w){ s0 += red[w * 64 + lane]; s1 += red[1024 + w * 64 + lane]; }
      float mean = s0 * (1.0f / 256.0f);
      float var  = s1 * (1.0f / 256.0f) - mean * mean;
      red[2048 + lane] = mean;
      red[2112 + lane] = rsqrtf(var + 1e-5f);
    }
    __syncthreads();
    const int pp = tid >> 4, qq = tid & 15;  // pixel, 16-ch group
    const float mn = red[2048 + pp], rs = red[2112 + pp];
    unsigned short* rowp = xn + pp * 264 + qq * 16;
    #pragma unroll
    for (int i = 0; i < 2; ++i){
      short8 v8 = *(short8*)(rowp + i * 8);
      #pragma unroll
      for (int e = 0; e < 8; ++e){
        float f = bf2f((unsigned short)v8[e]);
        v8[e] = (short)f2bf((f - mn) * rs);
      }
      *(short8*)(rowp + i * 8) = v8;
    }
  }
  __syncthreads();

  // ---- Phase 2: QKV projection (M=64, N=768, K=256); wave = (wm 0..1) x (wn 0..7) ----
  {
    const int wm = wv >> 3, wn = wv & 7;
    f32x4 acc[2][6];
    #pragma unroll
    for (int mt = 0; mt < 2; ++mt)
      #pragma unroll
      for (int nt = 0; nt < 6; ++nt)
        acc[mt][nt] = (f32x4){0.f, 0.f, 0.f, 0.f};
    #pragma unroll
    for (int kt = 0; kt < 8; ++kt){
      short8 a0 = *(const short8*)(xn + (wm * 32 +      l15) * 264 + kt * 32 + l4 * 8);
      short8 a1 = *(const short8*)(xn + (wm * 32 + 16 + l15) * 264 + kt * 32 + l4 * 8);
      const unsigned short* wp = wq_t + ((size_t)(wn * 6 * 8 + kt) * 64 + lane) * 8;
      short8 bb[6];
      #pragma unroll
      for (int nt = 0; nt < 6; ++nt) bb[nt] = *(const short8*)(wp + (size_t)nt * 4096);
      #pragma unroll
      for (int nt = 0; nt < 6; ++nt){
        acc[0][nt] = __builtin_amdgcn_mfma_f32_16x16x32_bf16(a0, bb[nt], acc[0][nt], 0, 0, 0);
        acc[1][nt] = __builtin_amdgcn_mfma_f32_16x16x32_bf16(a1, bb[nt], acc[1][nt], 0, 0, 0);
      }
    }
    #pragma unroll
    for (int nt = 0; nt < 6; ++nt){
      const int e = wn * 96 + nt * 16 + l15;
      const float bv = qkvb[e];
      #pragma unroll
      for (int mt = 0; mt < 2; ++mt){
        const int r0 = wm * 32 + mt * 16 + (l4 << 2);
        if (e < 512){
          unsigned short* dst = (e < 256) ? Qs : Ks;
          const int col = e & 255;
          #pragma unroll
          for (int j = 0; j < 4; ++j)
            dst[(r0 + j) * 264 + col] = f2bf(acc[mt][nt][j] + bv);
        } else {
          const int vd = e - 512;
          unsigned long long pk =
              (unsigned long long)f2bf(acc[mt][nt][0] + bv)
            | ((unsigned long long)f2bf(acc[mt][nt][1] + bv) << 16)
            | ((unsigned long long)f2bf(acc[mt][nt][2] + bv) << 32)
            | ((unsigned long long)f2bf(acc[mt][nt][3] + bv) << 48);
          *(unsigned long long*)(Vt + vd * 72 + r0) = pk;
        }
      }
    }
  }
  __syncthreads();

  // ---- Phase 3: attention; wave = (head h 0..7) x (row-half 0..1) ----
  {
    const int h = wv >> 1, half = wv & 1;
    short8 qa[2], kb[4];
    #pragma unroll
    for (int mt = 0; mt < 2; ++mt)
      qa[mt] = *(const short8*)(Qs + (half * 32 + mt * 16 + l15) * 264 + h * 32 + l4 * 8);
    #pragma unroll
    for (int t = 0; t < 4; ++t)
      kb[t] = *(const short8*)(Ks + (t * 16 + l15) * 264 + h * 32 + l4 * 8);
    __syncthreads();   // all Q/K fragments in regs -> xn+Qs region reusable as Pw

    unsigned short* Pw = (unsigned short*)smem + h * 4096;  // [64][64] swizzled
    #pragma unroll
    for (int mt = 0; mt < 2; ++mt){
      f32x4 srow[4];
      #pragma unroll
      for (int nt = 0; nt < 4; ++nt){
        f32x4 z = {0.f, 0.f, 0.f, 0.f};
        srow[nt] = __builtin_amdgcn_mfma_f32_16x16x32_bf16(qa[mt], kb[nt], z, 0, 0, 0);
      }
      #pragma unroll
      for (int j = 0; j < 4; ++j){
        const int row = half * 32 + mt * 16 + (l4 << 2) + j;
        float v0 = srow[0][j] + bias64[row * 64 +      l15];
        float v1 = srow[1][j] + bias64[row * 64 + 16 + l15];
        float v2 = srow[2][j] + bias64[row * 64 + 32 + l15];
        float v3 = srow[3][j] + bias64[row * 64 + 48 + l15];
        float m = fmaxf(fmaxf(v0, v1), fmaxf(v2, v3));
        m = fmaxf(m, __shfl_xor(m, 1)); m = fmaxf(m, __shfl_xor(m, 2));
        m = fmaxf(m, __shfl_xor(m, 4)); m = fmaxf(m, __shfl_xor(m, 8));
        v0 = __expf(v0 - m); v1 = __expf(v1 - m);
        v2 = __expf(v2 - m); v3 = __expf(v3 - m);
        float sm = v0 + v1 + v2 + v3;
        sm += __shfl_xor(sm, 1); sm += __shfl_xor(sm, 2);
        sm += __shfl_xor(sm, 4); sm += __shfl_xor(sm, 8);
        const float inv = 1.0f / sm;
        Pw[pswz(row,      l15)] = f2bf(v0 * inv);
        Pw[pswz(row, 16 + l15)] = f2bf(v1 * inv);
        Pw[pswz(row, 32 + l15)] = f2bf(v2 * inv);
        Pw[pswz(row, 48 + l15)] = f2bf(v3 * inv);
      }
    }
    f32x4 oacc[2][2];
    #pragma unroll
    for (int mt = 0; mt < 2; ++mt)
      #pragma unroll
      for (int nt = 0; nt < 2; ++nt)
        oacc[mt][nt] = (f32x4){0.f, 0.f, 0.f, 0.f};
    #pragma unroll
    for (int ktv = 0; ktv < 2; ++ktv){
      short8 pa[2], vb[2];
      #pragma unroll
      for (int mt = 0; mt < 2; ++mt){
        const int row = half * 32 + mt * 16 + l15;
        pa[mt] = *(const short8*)(Pw + row * 64 + (((ktv * 4 + l4) ^ (row & 7)) << 3));
      }
      #pragma unroll
      for (int nt = 0; nt < 2; ++nt)
        vb[nt] = *(const short8*)(Vt + (h * 32 + nt * 16 + l15) * 72 + ktv * 32 + l4 * 8);
      #pragma unroll
      for (int mt = 0; mt < 2; ++mt)
        #pragma unroll
        for (int nt = 0; nt < 2; ++nt)
          oacc[mt][nt] = __builtin_amdgcn_mfma_f32_16x16x32_bf16(pa[mt], vb[nt], oacc[mt][nt], 0, 0, 0);
    }
    __syncthreads();   // all PV reads done -> region 0 reusable as ao
    unsigned short* ao = (unsigned short*)smem;  // [64][264]
    #pragma unroll
    for (int mt = 0; mt < 2; ++mt)
      #pragma unroll
      for (int nt = 0; nt < 2; ++nt)
        #pragma unroll
        for (int j = 0; j < 4; ++j)
          ao[(half * 32 + mt * 16 + (l4 << 2) + j) * 264 + h * 32 + nt * 16 + l15] = f2bf(oacc[mt][nt][j]);
  }
  __syncthreads();

  // ---- Phase 4: out projection (M=64, N=256, K=256); wave = (wm 0..1) x (wn 0..7) ----
  {
    const int wm = wv >> 3, wn = wv & 7;
    const unsigned short* ao = (const unsigned short*)smem;
    float* sw = (float*)(smem + 33792) + wv * 288;  // [16][18] transpose scratch
    f32x4 acc[2][2];
    #pragma unroll
    for (int mt = 0; mt < 2; ++mt)
      #pragma unroll
      for (int nt = 0; nt < 2; ++nt)
        acc[mt][nt] = (f32x4){0.f, 0.f, 0.f, 0.f};
    #pragma unroll
    for (int kt = 0; kt < 8; ++kt){
      short8 a0 = *(const short8*)(ao + (wm * 32 +      l15) * 264 + kt * 32 + l4 * 8);
      short8 a1 = *(const short8*)(ao + (wm * 32 + 16 + l15) * 264 + kt * 32 + l4 * 8);
      const unsigned short* wp = wo_t + ((size_t)(wn * 2 * 8 + kt) * 64 + lane) * 8;
      short8 b0 = *(const short8*)(wp);
      short8 b1 = *(const short8*)(wp + 4096);
      acc[0][0] = __builtin_amdgcn_mfma_f32_16x16x32_bf16(a0, b0, acc[0][0], 0, 0, 0);
      acc[1][0] = __builtin_amdgcn_mfma_f32_16x16x32_bf16(a1, b0, acc[1][0], 0, 0, 0);
      acc[0][1] = __builtin_amdgcn_mfma_f32_16x16x32_bf16(a0, b1, acc[0][1], 0, 0, 0);
      acc[1][1] = __builtin_amdgcn_mfma_f32_16x16x32_bf16(a1, b1, acc[1][1], 0, 0, 0);
    }
    float* op = out + ((size_t)b << 24) + (size_t)(hb * 8) * 256 + (size_t)(wb * 8);
    #pragma unroll
    for (int nt = 0; nt < 2; ++nt){
      const int ebase = wn * 32 + nt * 16;
      const float bo = b_out[ebase + l15];
      #pragma unroll
      for (int mt = 0; mt < 2; ++mt){
        #pragma unroll
        for (int j = 0; j < 4; ++j)
          sw[((l4 << 2) + j) * 18 + l15] = acc[mt][nt][j] + bo;
        asm volatile("s_waitcnt lgkmcnt(0)" ::: "memory");
        #pragma unroll
        for (int q = 0; q < 4; ++q){
          const int el = q * 4 + l4;
          float v = sw[l15 * 18 + el];
          const int p = wm * 32 + mt * 16 + l15;
          op[(size_t)(ebase + el) * 65536 + (size_t)(p >> 3) * 256 + (p & 7)] = v;
        }
        asm volatile("s_waitcnt lgkmcnt(0)" ::: "memory");
      }
    }
  }
}

extern "C" void kernel_launch(void* const* d_in, const int* in_sizes, int n_in,
                              void* d_out, int out_size, void* d_ws, size_t ws_size,
                              hipStream_t stream){
  const float* x     = (const float*)d_in[0];
  const float* g     = (const float*)d_in[1];
  const float* bvec  = (const float*)d_in[2];
  const float* w_qkv = (const float*)d_in[3];
  const float* w_out = (const float*)d_in[4];
  const float* b_out = (const float*)d_in[5];
  float* out = (float*)d_out;

  char* ws = (char*)d_ws;
  unsigned short* wq_t  = (unsigned short*)(ws);            // 768*256 bf16 tiled
  unsigned short* wo_t  = (unsigned short*)(ws + 393216);   // 256*256 bf16 tiled
  float* qkvb   = (float*)(ws + 524288);                    // 768 f32
  float* table  = (float*)(ws + 527360);                    // 289 f32
  float* bias64 = (float*)(ws + 528640);                    // 4096 f32

  prep_tiled<<<dim3(128), dim3(256), 0, stream>>>(w_qkv, g, w_out, wq_t, wo_t);
  qkvb_kernel<<<dim3(192), dim3(256), 0, stream>>>(w_qkv, bvec, qkvb);
  dpb_kernel<<<dim3(289), dim3(64), 0, stream>>>(
      (const float*)d_in[6],  (const float*)d_in[7],  (const float*)d_in[8],  (const float*)d_in[9],
      (const float*)d_in[10], (const float*)d_in[11], (const float*)d_in[12], (const float*)d_in[13],
      (const float*)d_in[14], (const float*)d_in[15], (const float*)d_in[16], (const float*)d_in[17],
      (const float*)d_in[18], (const float*)d_in[19], table);
  bias_expand<<<dim3(16), dim3(256), 0, stream>>>(table, bias64);

  hipFuncSetAttribute((const void*)attn_main, hipFuncAttributeMaxDynamicSharedMemorySize, LDS_TOTAL);
  attn_main<<<dim3(4096), dim3(1024), LDS_TOTAL, stream>>>(x, wq_t, wo_t, qkvb, b_out, bias64, out);
}